// Round 3
// baseline (749.269 us; speedup 1.0000x reference)
//
#include <hip/hip_runtime.h>
#include <hip/hip_bf16.h>

typedef short  bf16x8 __attribute__((ext_vector_type(8)));
typedef float  f32x4  __attribute__((ext_vector_type(4)));
typedef unsigned int u32;

#define MFMA16(A,B,C) __builtin_amdgcn_mfma_f32_16x16x32_bf16((A),(B),(C),0,0,0)

__device__ __forceinline__ unsigned short f2bfu(float f) {
  __hip_bfloat16 h = __float2bfloat16(f);
  unsigned short u; __builtin_memcpy(&u, &h, 2); return u;
}
__device__ __forceinline__ u32 packbf(float lo, float hi) {
  return (u32)f2bfu(lo) | ((u32)f2bfu(hi) << 16);
}
__device__ __forceinline__ float bfs(unsigned short u) {   // bf16 -> f32 (exact)
  return __uint_as_float(((u32)u) << 16);
}
__device__ __forceinline__ float bflo(u32 v) { return __uint_as_float(v << 16); }
__device__ __forceinline__ float bfhi(u32 v) { return __uint_as_float(v & 0xffff0000u); }
__device__ __forceinline__ bf16x8 mk8(u32 a, u32 b, u32 c, u32 d) {
  union { bf16x8 h; u32 u[4]; } t; t.u[0] = a; t.u[1] = b; t.u[2] = c; t.u[3] = d; return t.h;
}
// swizzled byte address for element (row, byte-col) of a [64][128] bf16 LDS tile
__device__ __forceinline__ int swz(int row, int colb) {
  return row * 256 + (colb ^ ((row & 7) << 4));
}

// ---------------- LDS layout ----------------
// [0,16384):      xb  = x bf16 [64][128] (swizzled)        live whole kernel
// [16384,32768):  ca  = ctx bf16 -> att bf16 (in-place)    (swizzled)
// [32768,39424):  awlog(256) aw(256) parts(4096) pooled(2048)
constexpr int CTX_OFF = 16384;
constexpr int F_OFF   = 32768;
constexpr int SMEM_BYTES = 39424;

// pre-kernel: convert W_in [384*128] + W_out [128*128] fp32 -> bf16 into d_ws
__global__ void wconv_kernel(const float* __restrict__ win, const float* __restrict__ wout,
                             unsigned short* __restrict__ dst) {
  int i = blockIdx.x * 256 + threadIdx.x;   // 256x256 = 65536 exact
  float v = (i < 49152) ? win[i] : wout[i - 49152];
  dst[i] = f2bfu(v);
}

__global__ __launch_bounds__(256, 4)
void fused_mol_kernel(const float* __restrict__ xg_all,
                      const unsigned short* __restrict__ wb,   // W_in bf16 [384][128], W_out bf16 [128][128]
                      const float* __restrict__ b_in,
                      const float* __restrict__ b_out,
                      const float* __restrict__ W_pool,
                      const float* __restrict__ b_pool,
                      float* __restrict__ out)
{
  __shared__ __align__(16) char smem[SMEM_BYTES];
  const int tid  = threadIdx.x;
  const int w    = tid >> 6;        // wave id == head id
  const int lane = tid & 63;
  const int lr   = lane & 15;
  const int lq   = lane >> 4;
  const long b   = blockIdx.x;

  char* xb = smem;
  char* ca = smem + CTX_OFF;
  float* awlog  = (float*)(smem + F_OFF);
  float* aw     = (float*)(smem + F_OFF + 256);
  float* parts  = (float*)(smem + F_OFF + 512);
  float* pooled = (float*)(smem + F_OFF + 4608);

  // ================= Phase 0: x -> xb (bf16, swizzled) =================
  const float* xg = xg_all + b * (64 * 128);
  #pragma unroll
  for (int i = 0; i < 8; ++i) {
    int f = i * 1024 + tid * 4;
    float4 v = *(const float4*)(xg + f);
    int row = f >> 7, col = f & 127;
    uint2 d; d.x = packbf(v.x, v.y); d.y = packbf(v.z, v.w);
    *(uint2*)(xb + swz(row, col * 2)) = d;
  }
  __syncthreads();

  // ================= Phase 1a: Q^T,K^T = W_{q,k}[head w] @ x^T (in regs) =================
  // C layout per 16x16 tile: lane holds col=lr (atom), rows = lq*4+r (dh).
  u32 Qpk[2][4][2], Kpk[2][4][2];   // [dh-tile i][atom-tile j][dw]
  {
    f32x4 aq[2][4], ak[2][4];
    #pragma unroll
    for (int i = 0; i < 2; ++i)
      #pragma unroll
      for (int j = 0; j < 4; ++j) { aq[i][j] = (f32x4){0,0,0,0}; ak[i][j] = (f32x4){0,0,0,0}; }
    #pragma unroll
    for (int kk = 0; kk < 4; ++kk) {
      bf16x8 Bx[4];
      #pragma unroll
      for (int j = 0; j < 4; ++j)
        Bx[j] = *(const bf16x8*)(xb + swz(16 * j + lr, (kk * 32 + lq * 8) * 2));
      bf16x8 Aq[2], Ak[2];
      #pragma unroll
      for (int i = 0; i < 2; ++i) {
        Aq[i] = *(const bf16x8*)(wb + (w * 32 + 16 * i + lr) * 128 + kk * 32 + lq * 8);
        Ak[i] = *(const bf16x8*)(wb + (128 + w * 32 + 16 * i + lr) * 128 + kk * 32 + lq * 8);
      }
      #pragma unroll
      for (int i = 0; i < 2; ++i)
        #pragma unroll
        for (int j = 0; j < 4; ++j) {
          aq[i][j] = MFMA16(Aq[i], Bx[j], aq[i][j]);
          ak[i][j] = MFMA16(Ak[i], Bx[j], ak[i][j]);
        }
    }
    const float sc = 0.17677669529663687f;   // 1/sqrt(32), folded into Q
    #pragma unroll
    for (int i = 0; i < 2; ++i) {
      float bq[4], bk[4];
      #pragma unroll
      for (int r = 0; r < 4; ++r) {
        bq[r] = b_in[w * 32 + 16 * i + lq * 4 + r];
        bk[r] = b_in[128 + w * 32 + 16 * i + lq * 4 + r];
      }
      #pragma unroll
      for (int j = 0; j < 4; ++j) {
        Qpk[i][j][0] = packbf((aq[i][j][0] + bq[0]) * sc, (aq[i][j][1] + bq[1]) * sc);
        Qpk[i][j][1] = packbf((aq[i][j][2] + bq[2]) * sc, (aq[i][j][3] + bq[3]) * sc);
        Kpk[i][j][0] = packbf(ak[i][j][0] + bk[0], ak[i][j][1] + bk[1]);
        Kpk[i][j][1] = packbf(ak[i][j][2] + bk[2], ak[i][j][3] + bk[3]);
      }
    }
  }

  // ================= Phase 2: sT[m][l] = sum_dh K^T[dh][m] * Q^T[dh][l] =================
  // Both operands are repacked C-tiles; identical k-permutation rho on both sides.
  f32x4 sT[4][4];
  {
    const f32x4 z = (f32x4){0, 0, 0, 0};
    #pragma unroll
    for (int mt = 0; mt < 4; ++mt) {
      bf16x8 Ka = mk8(Kpk[0][mt][0], Kpk[0][mt][1], Kpk[1][mt][0], Kpk[1][mt][1]);
      #pragma unroll
      for (int nt = 0; nt < 4; ++nt) {
        bf16x8 Qb = mk8(Qpk[0][nt][0], Qpk[0][nt][1], Qpk[1][nt][0], Qpk[1][nt][1]);
        sT[mt][nt] = MFMA16(Ka, Qb, z);
      }
    }
  }

  // ---- softmax over m (rows); column l = lr lane-local, combine across lq via shfl ----
  u32 Ppk[4][4][2];
  #pragma unroll
  for (int nt = 0; nt < 4; ++nt) {
    float mx = -1e30f;
    #pragma unroll
    for (int mt = 0; mt < 4; ++mt)
      #pragma unroll
      for (int r = 0; r < 4; ++r) mx = fmaxf(mx, sT[mt][nt][r]);
    mx = fmaxf(mx, __shfl_xor(mx, 16));
    mx = fmaxf(mx, __shfl_xor(mx, 32));
    float ex[4][4]; float s = 0.f;
    #pragma unroll
    for (int mt = 0; mt < 4; ++mt)
      #pragma unroll
      for (int r = 0; r < 4; ++r) { ex[mt][r] = __expf(sT[mt][nt][r] - mx); s += ex[mt][r]; }
    s += __shfl_xor(s, 16);
    s += __shfl_xor(s, 32);
    float inv = 1.f / s;
    #pragma unroll
    for (int mt = 0; mt < 4; ++mt) {
      Ppk[mt][nt][0] = packbf(ex[mt][0] * inv, ex[mt][1] * inv);
      Ppk[mt][nt][1] = packbf(ex[mt][2] * inv, ex[mt][3] * inv);
    }
  }

  // ================= Phase 1b: V = x @ Wv[head w]^T (C[atom][dh] in regs) =================
  u32 Vpk[4][2][2];   // [atom-tile m][dh-tile j][dw]
  {
    f32x4 av[4][2];
    #pragma unroll
    for (int m = 0; m < 4; ++m)
      #pragma unroll
      for (int j = 0; j < 2; ++j) av[m][j] = (f32x4){0, 0, 0, 0};
    #pragma unroll
    for (int kk = 0; kk < 4; ++kk) {
      bf16x8 Ax[4];
      #pragma unroll
      for (int m = 0; m < 4; ++m)
        Ax[m] = *(const bf16x8*)(xb + swz(16 * m + lr, (kk * 32 + lq * 8) * 2));
      bf16x8 Bw[2];
      #pragma unroll
      for (int j = 0; j < 2; ++j)
        Bw[j] = *(const bf16x8*)(wb + (256 + w * 32 + 16 * j + lr) * 128 + kk * 32 + lq * 8);
      #pragma unroll
      for (int m = 0; m < 4; ++m)
        #pragma unroll
        for (int j = 0; j < 2; ++j) av[m][j] = MFMA16(Ax[m], Bw[j], av[m][j]);
    }
    #pragma unroll
    for (int j = 0; j < 2; ++j) {
      float bv = b_in[256 + w * 32 + 16 * j + lr];
      #pragma unroll
      for (int m = 0; m < 4; ++m) {
        Vpk[m][j][0] = packbf(av[m][j][0] + bv, av[m][j][1] + bv);
        Vpk[m][j][1] = packbf(av[m][j][2] + bv, av[m][j][3] + bv);
      }
    }
  }

  // ================= Phase 3: ctx[l][dh] = sum_m P^T[m][l] * V[m][dh] =================
  {
    f32x4 cacc[4][2];
    #pragma unroll
    for (int nt = 0; nt < 4; ++nt)
      #pragma unroll
      for (int j = 0; j < 2; ++j) cacc[nt][j] = (f32x4){0, 0, 0, 0};
    #pragma unroll
    for (int kk = 0; kk < 2; ++kk) {
      #pragma unroll
      for (int nt = 0; nt < 4; ++nt) {
        bf16x8 Pa = mk8(Ppk[2 * kk][nt][0], Ppk[2 * kk][nt][1],
                        Ppk[2 * kk + 1][nt][0], Ppk[2 * kk + 1][nt][1]);
        #pragma unroll
        for (int j = 0; j < 2; ++j) {
          bf16x8 Vb = mk8(Vpk[2 * kk][j][0], Vpk[2 * kk][j][1],
                          Vpk[2 * kk + 1][j][0], Vpk[2 * kk + 1][j][1]);
          cacc[nt][j] = MFMA16(Pa, Vb, cacc[nt][j]);
        }
      }
    }
    // write ctx (bf16, swizzled): col dh_global = 32w+16j+lr, rows l = 16nt+lq*4+r
    #pragma unroll
    for (int nt = 0; nt < 4; ++nt)
      #pragma unroll
      for (int j = 0; j < 2; ++j) {
        int dhg = w * 32 + 16 * j + lr;
        #pragma unroll
        for (int r = 0; r < 4; ++r)
          *(unsigned short*)(ca + swz(16 * nt + lq * 4 + r, dhg * 2)) = f2bfu(cacc[nt][j][r]);
      }
  }
  __syncthreads();

  // ================= Phase 4: att = ctx @ W_out^T + b_out (in-place, per-wave rows) =====
  {
    bf16x8 Actx[4];
    #pragma unroll
    for (int kk = 0; kk < 4; ++kk)
      Actx[kk] = *(const bf16x8*)(ca + swz(16 * w + lr, (kk * 32 + lq * 8) * 2));
    const unsigned short* wout = wb + 49152;
    #pragma unroll
    for (int nt = 0; nt < 8; ++nt) {
      bf16x8 Bw[4];
      #pragma unroll
      for (int kk = 0; kk < 4; ++kk)
        Bw[kk] = *(const bf16x8*)(wout + (16 * nt + lr) * 128 + kk * 32 + lq * 8);
      f32x4 a = (f32x4){0, 0, 0, 0};
      #pragma unroll
      for (int kk = 0; kk < 4; ++kk) a = MFMA16(Actx[kk], Bw[kk], a);
      float bo = b_out[16 * nt + lr];
      int e = 16 * nt + lr;
      #pragma unroll
      for (int r = 0; r < 4; ++r)
        *(unsigned short*)(ca + swz(16 * w + lq * 4 + r, e * 2)) = f2bfu(a[r] + bo);
    }
  }
  __syncthreads();

  // ================= Phase 5: pooling =================
  {  // aw logits: 4 threads per row
    int l = tid >> 2, q = tid & 3;
    float s = 0.f;
    #pragma unroll
    for (int jj = 0; jj < 8; ++jj) {
      int colb = (q * 32 + jj * 4) * 2;
      uint2 av = *(const uint2*)(ca + swz(l, colb));
      uint2 xv = *(const uint2*)(xb + swz(l, colb));
      s += bflo(av.x) * bflo(xv.x) + bfhi(av.x) * bfhi(xv.x)
         + bflo(av.y) * bflo(xv.y) + bfhi(av.y) * bfhi(xv.y);
    }
    s += __shfl_xor(s, 1);
    s += __shfl_xor(s, 2);
    if (q == 0) awlog[l] = s;
  }
  __syncthreads();
  if (tid < 64) {   // wave0: parallel softmax over 64 logits
    float v = awlog[tid];
    float mx = v;
    #pragma unroll
    for (int o = 1; o < 64; o <<= 1) mx = fmaxf(mx, __shfl_xor(mx, o));
    float e = __expf(v - mx);
    float s = e;
    #pragma unroll
    for (int o = 1; o < 64; o <<= 1) s += __shfl_xor(s, o);
    aw[tid] = e / s;
  }
  __syncthreads();
  {  // per-column stats, 2 threads per column
    int e = tid & 127, hf = tid >> 7;
    float mx = -1e30f, s = 0.f, s2 = 0.f, ws = 0.f;
    for (int i = 0; i < 32; ++i) {
      int l = hf * 32 + i;
      float a = bfs(*(const unsigned short*)(ca + swz(l, e * 2)));
      float wgt = aw[l];
      mx = fmaxf(mx, a); s += a; s2 += a * a; ws += a * wgt;
    }
    float4 pr; pr.x = mx; pr.y = s; pr.z = s2; pr.w = ws;
    *(float4*)(parts + (hf * 128 + e) * 4) = pr;
  }
  __syncthreads();
  if (tid < 128) {
    int e = tid;
    float4 p0 = *(const float4*)(parts + e * 4);
    float4 p1 = *(const float4*)(parts + (128 + e) * 4);
    float mx = fmaxf(p0.x, p1.x);
    float s = p0.y + p1.y, s2 = p0.z + p1.z, ws = p0.w + p1.w;
    float mean = s * (1.f / 64.f);
    float var = (s2 - s * mean) * (1.f / 63.f);
    var = fmaxf(var, 0.f);
    pooled[0 * 128 + e] = ws;
    pooled[1 * 128 + e] = mx;
    pooled[2 * 128 + e] = mean;
    pooled[3 * 128 + e] = sqrtf(var);
  }
  __syncthreads();

  // ================= Phase 6: 4 small projections =================
  if (tid < 64) {
    int pp = tid >> 4;
    float acc = b_pool[tid];
    const float* wr = W_pool + tid * 128;
    #pragma unroll 8
    for (int d = 0; d < 128; d += 4) {
      float4 wv = *(const float4*)(wr + d);
      float4 pl = *(const float4*)(pooled + pp * 128 + d);
      acc += wv.x * pl.x + wv.y * pl.y + wv.z * pl.z + wv.w * pl.w;
    }
    out[b * 64 + tid] = acc;
  }
}

extern "C" void kernel_launch(void* const* d_in, const int* in_sizes, int n_in,
                              void* d_out, int out_size, void* d_ws, size_t ws_size,
                              hipStream_t stream) {
  const float* x      = (const float*)d_in[0];
  // d_in[1] = batch_indices (unused: equal-length segments)
  const float* W_in   = (const float*)d_in[2];
  const float* b_in   = (const float*)d_in[3];
  const float* W_out  = (const float*)d_in[4];
  const float* b_out  = (const float*)d_in[5];
  const float* W_pool = (const float*)d_in[6];
  const float* b_pool = (const float*)d_in[7];
  unsigned short* wb = (unsigned short*)d_ws;   // 65536 bf16 = 128 KiB

  hipLaunchKernelGGL(wconv_kernel, dim3(256), dim3(256), 0, stream, W_in, W_out, wb);
  hipLaunchKernelGGL(fused_mol_kernel, dim3(8192), dim3(256), 0, stream,
                     x, wb, b_in, b_out, W_pool, b_pool, (float*)d_out);
}

// Round 4
// 573.291 us; speedup vs baseline: 1.3070x; 1.3070x over previous
//
#include <hip/hip_runtime.h>
#include <hip/hip_bf16.h>

typedef short  bf16x8 __attribute__((ext_vector_type(8)));
typedef float  f32x4  __attribute__((ext_vector_type(4)));
typedef unsigned int u32;

#define MFMA16(A,B,C) __builtin_amdgcn_mfma_f32_16x16x32_bf16((A),(B),(C),0,0,0)

__device__ __forceinline__ unsigned short f2bfu(float f) {
  __hip_bfloat16 h = __float2bfloat16(f);
  unsigned short u; __builtin_memcpy(&u, &h, 2); return u;
}
__device__ __forceinline__ u32 packbf(float lo, float hi) {
  return (u32)f2bfu(lo) | ((u32)f2bfu(hi) << 16);
}
__device__ __forceinline__ float bfs(unsigned short u) {   // bf16 -> f32 (exact)
  return __uint_as_float(((u32)u) << 16);
}
__device__ __forceinline__ float bflo(u32 v) { return __uint_as_float(v << 16); }
__device__ __forceinline__ float bfhi(u32 v) { return __uint_as_float(v & 0xffff0000u); }
__device__ __forceinline__ bf16x8 mk8(u32 a, u32 b, u32 c, u32 d) {
  union { bf16x8 h; u32 u[4]; } t; t.u[0] = a; t.u[1] = b; t.u[2] = c; t.u[3] = d; return t.h;
}
// swizzled byte address for element (row, byte-col) of a [64][128] bf16 LDS tile
__device__ __forceinline__ int swz(int row, int colb) {
  return row * 256 + (colb ^ ((row & 7) << 4));
}

// ---------------- LDS layout ----------------
// [0,16384):      xb  = x bf16 [64][128] (swizzled)        live whole kernel
// [16384,32768):  ca  = ctx bf16 -> att bf16 (in-place)    (swizzled)
// [32768,39424):  awlog(256) aw(256) parts(4096) pooled(2048)
constexpr int CTX_OFF = 16384;
constexpr int F_OFF   = 32768;
constexpr int SMEM_BYTES = 39424;

// pre-kernel: convert W_in [384*128] + W_out [128*128] fp32 -> bf16 into d_ws
__global__ void wconv_kernel(const float* __restrict__ win, const float* __restrict__ wout,
                             unsigned short* __restrict__ dst) {
  int i = blockIdx.x * 256 + threadIdx.x;   // 256x256 = 65536 exact
  float v = (i < 49152) ? win[i] : wout[i - 49152];
  dst[i] = f2bfu(v);
}

// launch_bounds(256,3): unified VGPR budget 512/3 ~= 170/wave. Demand ~120 ->
// no scratch spills (round-3's (256,4) cap of 128 spilled 862 MB to scratch).
__global__ __launch_bounds__(256, 3)
void fused_mol_kernel(const float* __restrict__ xg_all,
                      const unsigned short* __restrict__ wb,   // W_in bf16 [384][128], W_out bf16 [128][128]
                      const float* __restrict__ b_in,
                      const float* __restrict__ b_out,
                      const float* __restrict__ W_pool,
                      const float* __restrict__ b_pool,
                      float* __restrict__ out)
{
  __shared__ __align__(16) char smem[SMEM_BYTES];
  const int tid  = threadIdx.x;
  const int w    = tid >> 6;        // wave id == head id
  const int lane = tid & 63;
  const int lr   = lane & 15;
  const int lq   = lane >> 4;
  const long b   = blockIdx.x;

  char* xb = smem;
  char* ca = smem + CTX_OFF;
  float* awlog  = (float*)(smem + F_OFF);
  float* aw     = (float*)(smem + F_OFF + 256);
  float* parts  = (float*)(smem + F_OFF + 512);
  float* pooled = (float*)(smem + F_OFF + 4608);

  // ================= Phase 0: x -> xb (bf16, swizzled) =================
  const float* xg = xg_all + b * (64 * 128);
  #pragma unroll
  for (int i = 0; i < 8; ++i) {
    int f = i * 1024 + tid * 4;
    float4 v = *(const float4*)(xg + f);
    int row = f >> 7, col = f & 127;
    uint2 d; d.x = packbf(v.x, v.y); d.y = packbf(v.z, v.w);
    *(uint2*)(xb + swz(row, col * 2)) = d;
  }
  __syncthreads();

  // ================= Phase 1a: K^T then Q^T = W @ x^T (in regs, split passes) ==========
  // C layout per 16x16 tile: lane holds col=lr (atom), rows = lq*4+r (dh).
  u32 Qpk[2][4][2], Kpk[2][4][2];   // [dh-tile i][atom-tile j][dw]
  {
    // ---- K pass ----
    f32x4 ak[2][4];
    #pragma unroll
    for (int i = 0; i < 2; ++i)
      #pragma unroll
      for (int j = 0; j < 4; ++j) ak[i][j] = (f32x4){0, 0, 0, 0};
    #pragma unroll
    for (int kk = 0; kk < 4; ++kk) {
      bf16x8 Bx[4];
      #pragma unroll
      for (int j = 0; j < 4; ++j)
        Bx[j] = *(const bf16x8*)(xb + swz(16 * j + lr, (kk * 32 + lq * 8) * 2));
      bf16x8 Ak[2];
      #pragma unroll
      for (int i = 0; i < 2; ++i)
        Ak[i] = *(const bf16x8*)(wb + (128 + w * 32 + 16 * i + lr) * 128 + kk * 32 + lq * 8);
      #pragma unroll
      for (int i = 0; i < 2; ++i)
        #pragma unroll
        for (int j = 0; j < 4; ++j) ak[i][j] = MFMA16(Ak[i], Bx[j], ak[i][j]);
    }
    #pragma unroll
    for (int i = 0; i < 2; ++i) {
      float bk[4];
      #pragma unroll
      for (int r = 0; r < 4; ++r) bk[r] = b_in[128 + w * 32 + 16 * i + lq * 4 + r];
      #pragma unroll
      for (int j = 0; j < 4; ++j) {
        Kpk[i][j][0] = packbf(ak[i][j][0] + bk[0], ak[i][j][1] + bk[1]);
        Kpk[i][j][1] = packbf(ak[i][j][2] + bk[2], ak[i][j][3] + bk[3]);
      }
    }
    // ---- Q pass ----
    f32x4 aq[2][4];
    #pragma unroll
    for (int i = 0; i < 2; ++i)
      #pragma unroll
      for (int j = 0; j < 4; ++j) aq[i][j] = (f32x4){0, 0, 0, 0};
    #pragma unroll
    for (int kk = 0; kk < 4; ++kk) {
      bf16x8 Bx[4];
      #pragma unroll
      for (int j = 0; j < 4; ++j)
        Bx[j] = *(const bf16x8*)(xb + swz(16 * j + lr, (kk * 32 + lq * 8) * 2));
      bf16x8 Aq[2];
      #pragma unroll
      for (int i = 0; i < 2; ++i)
        Aq[i] = *(const bf16x8*)(wb + (w * 32 + 16 * i + lr) * 128 + kk * 32 + lq * 8);
      #pragma unroll
      for (int i = 0; i < 2; ++i)
        #pragma unroll
        for (int j = 0; j < 4; ++j) aq[i][j] = MFMA16(Aq[i], Bx[j], aq[i][j]);
    }
    const float sc = 0.17677669529663687f;   // 1/sqrt(32), folded into Q
    #pragma unroll
    for (int i = 0; i < 2; ++i) {
      float bq[4];
      #pragma unroll
      for (int r = 0; r < 4; ++r) bq[r] = b_in[w * 32 + 16 * i + lq * 4 + r];
      #pragma unroll
      for (int j = 0; j < 4; ++j) {
        Qpk[i][j][0] = packbf((aq[i][j][0] + bq[0]) * sc, (aq[i][j][1] + bq[1]) * sc);
        Qpk[i][j][1] = packbf((aq[i][j][2] + bq[2]) * sc, (aq[i][j][3] + bq[3]) * sc);
      }
    }
  }

  // ================= Phase 2: sT[m][l] = sum_dh K^T[dh][m] * Q^T[dh][l] =================
  // Both operands are repacked C-tiles; identical k-permutation rho on both sides.
  f32x4 sT[4][4];
  {
    const f32x4 z = (f32x4){0, 0, 0, 0};
    #pragma unroll
    for (int mt = 0; mt < 4; ++mt) {
      bf16x8 Ka = mk8(Kpk[0][mt][0], Kpk[0][mt][1], Kpk[1][mt][0], Kpk[1][mt][1]);
      #pragma unroll
      for (int nt = 0; nt < 4; ++nt) {
        bf16x8 Qb = mk8(Qpk[0][nt][0], Qpk[0][nt][1], Qpk[1][nt][0], Qpk[1][nt][1]);
        sT[mt][nt] = MFMA16(Ka, Qb, z);
      }
    }
  }

  // ---- softmax over m (rows); column l = lr lane-local, combine across lq via shfl ----
  u32 Ppk[4][4][2];
  #pragma unroll
  for (int nt = 0; nt < 4; ++nt) {
    float mx = -1e30f;
    #pragma unroll
    for (int mt = 0; mt < 4; ++mt)
      #pragma unroll
      for (int r = 0; r < 4; ++r) mx = fmaxf(mx, sT[mt][nt][r]);
    mx = fmaxf(mx, __shfl_xor(mx, 16));
    mx = fmaxf(mx, __shfl_xor(mx, 32));
    float ex[4][4]; float s = 0.f;
    #pragma unroll
    for (int mt = 0; mt < 4; ++mt)
      #pragma unroll
      for (int r = 0; r < 4; ++r) { ex[mt][r] = __expf(sT[mt][nt][r] - mx); s += ex[mt][r]; }
    s += __shfl_xor(s, 16);
    s += __shfl_xor(s, 32);
    float inv = 1.f / s;
    #pragma unroll
    for (int mt = 0; mt < 4; ++mt) {
      Ppk[mt][nt][0] = packbf(ex[mt][0] * inv, ex[mt][1] * inv);
      Ppk[mt][nt][1] = packbf(ex[mt][2] * inv, ex[mt][3] * inv);
    }
  }

  // ================= Phase 1b: V = x @ Wv[head w]^T (C[atom][dh] in regs) =================
  u32 Vpk[4][2][2];   // [atom-tile m][dh-tile j][dw]
  {
    f32x4 av[4][2];
    #pragma unroll
    for (int m = 0; m < 4; ++m)
      #pragma unroll
      for (int j = 0; j < 2; ++j) av[m][j] = (f32x4){0, 0, 0, 0};
    #pragma unroll
    for (int kk = 0; kk < 4; ++kk) {
      bf16x8 Ax[4];
      #pragma unroll
      for (int m = 0; m < 4; ++m)
        Ax[m] = *(const bf16x8*)(xb + swz(16 * m + lr, (kk * 32 + lq * 8) * 2));
      bf16x8 Bw[2];
      #pragma unroll
      for (int j = 0; j < 2; ++j)
        Bw[j] = *(const bf16x8*)(wb + (256 + w * 32 + 16 * j + lr) * 128 + kk * 32 + lq * 8);
      #pragma unroll
      for (int m = 0; m < 4; ++m)
        #pragma unroll
        for (int j = 0; j < 2; ++j) av[m][j] = MFMA16(Ax[m], Bw[j], av[m][j]);
    }
    #pragma unroll
    for (int j = 0; j < 2; ++j) {
      float bv = b_in[256 + w * 32 + 16 * j + lr];
      #pragma unroll
      for (int m = 0; m < 4; ++m) {
        Vpk[m][j][0] = packbf(av[m][j][0] + bv, av[m][j][1] + bv);
        Vpk[m][j][1] = packbf(av[m][j][2] + bv, av[m][j][3] + bv);
      }
    }
  }

  // ================= Phase 3: ctx[l][dh] = sum_m P^T[m][l] * V[m][dh] =================
  {
    f32x4 cacc[4][2];
    #pragma unroll
    for (int nt = 0; nt < 4; ++nt)
      #pragma unroll
      for (int j = 0; j < 2; ++j) cacc[nt][j] = (f32x4){0, 0, 0, 0};
    #pragma unroll
    for (int kk = 0; kk < 2; ++kk) {
      #pragma unroll
      for (int nt = 0; nt < 4; ++nt) {
        bf16x8 Pa = mk8(Ppk[2 * kk][nt][0], Ppk[2 * kk][nt][1],
                        Ppk[2 * kk + 1][nt][0], Ppk[2 * kk + 1][nt][1]);
        #pragma unroll
        for (int j = 0; j < 2; ++j) {
          bf16x8 Vb = mk8(Vpk[2 * kk][j][0], Vpk[2 * kk][j][1],
                          Vpk[2 * kk + 1][j][0], Vpk[2 * kk + 1][j][1]);
          cacc[nt][j] = MFMA16(Pa, Vb, cacc[nt][j]);
        }
      }
    }
    // write ctx (bf16, swizzled): col dh_global = 32w+16j+lr, rows l = 16nt+lq*4+r
    #pragma unroll
    for (int nt = 0; nt < 4; ++nt)
      #pragma unroll
      for (int j = 0; j < 2; ++j) {
        int dhg = w * 32 + 16 * j + lr;
        #pragma unroll
        for (int r = 0; r < 4; ++r)
          *(unsigned short*)(ca + swz(16 * nt + lq * 4 + r, dhg * 2)) = f2bfu(cacc[nt][j][r]);
      }
  }
  __syncthreads();

  // ================= Phase 4: att = ctx @ W_out^T + b_out (in-place, per-wave rows) =====
  {
    bf16x8 Actx[4];
    #pragma unroll
    for (int kk = 0; kk < 4; ++kk)
      Actx[kk] = *(const bf16x8*)(ca + swz(16 * w + lr, (kk * 32 + lq * 8) * 2));
    const unsigned short* wout = wb + 49152;
    #pragma unroll
    for (int nt = 0; nt < 8; ++nt) {
      bf16x8 Bw[4];
      #pragma unroll
      for (int kk = 0; kk < 4; ++kk)
        Bw[kk] = *(const bf16x8*)(wout + (16 * nt + lr) * 128 + kk * 32 + lq * 8);
      f32x4 a = (f32x4){0, 0, 0, 0};
      #pragma unroll
      for (int kk = 0; kk < 4; ++kk) a = MFMA16(Actx[kk], Bw[kk], a);
      float bo = b_out[16 * nt + lr];
      int e = 16 * nt + lr;
      #pragma unroll
      for (int r = 0; r < 4; ++r)
        *(unsigned short*)(ca + swz(16 * w + lq * 4 + r, e * 2)) = f2bfu(a[r] + bo);
    }
  }
  __syncthreads();

  // ================= Phase 5: pooling =================
  {  // aw logits: 4 threads per row
    int l = tid >> 2, q = tid & 3;
    float s = 0.f;
    #pragma unroll
    for (int jj = 0; jj < 8; ++jj) {
      int colb = (q * 32 + jj * 4) * 2;
      uint2 av = *(const uint2*)(ca + swz(l, colb));
      uint2 xv = *(const uint2*)(xb + swz(l, colb));
      s += bflo(av.x) * bflo(xv.x) + bfhi(av.x) * bfhi(xv.x)
         + bflo(av.y) * bflo(xv.y) + bfhi(av.y) * bfhi(xv.y);
    }
    s += __shfl_xor(s, 1);
    s += __shfl_xor(s, 2);
    if (q == 0) awlog[l] = s;
  }
  __syncthreads();
  if (tid < 64) {   // wave0: parallel softmax over 64 logits
    float v = awlog[tid];
    float mx = v;
    #pragma unroll
    for (int o = 1; o < 64; o <<= 1) mx = fmaxf(mx, __shfl_xor(mx, o));
    float e = __expf(v - mx);
    float s = e;
    #pragma unroll
    for (int o = 1; o < 64; o <<= 1) s += __shfl_xor(s, o);
    aw[tid] = e / s;
  }
  __syncthreads();
  {  // per-column stats, 2 threads per column
    int e = tid & 127, hf = tid >> 7;
    float mx = -1e30f, s = 0.f, s2 = 0.f, ws = 0.f;
    for (int i = 0; i < 32; ++i) {
      int l = hf * 32 + i;
      float a = bfs(*(const unsigned short*)(ca + swz(l, e * 2)));
      float wgt = aw[l];
      mx = fmaxf(mx, a); s += a; s2 += a * a; ws += a * wgt;
    }
    float4 pr; pr.x = mx; pr.y = s; pr.z = s2; pr.w = ws;
    *(float4*)(parts + (hf * 128 + e) * 4) = pr;
  }
  __syncthreads();
  if (tid < 128) {
    int e = tid;
    float4 p0 = *(const float4*)(parts + e * 4);
    float4 p1 = *(const float4*)(parts + (128 + e) * 4);
    float mx = fmaxf(p0.x, p1.x);
    float s = p0.y + p1.y, s2 = p0.z + p1.z, ws = p0.w + p1.w;
    float mean = s * (1.f / 64.f);
    float var = (s2 - s * mean) * (1.f / 63.f);
    var = fmaxf(var, 0.f);
    pooled[0 * 128 + e] = ws;
    pooled[1 * 128 + e] = mx;
    pooled[2 * 128 + e] = mean;
    pooled[3 * 128 + e] = sqrtf(var);
  }
  __syncthreads();

  // ================= Phase 6: 4 small projections =================
  if (tid < 64) {
    int pp = tid >> 4;
    float acc = b_pool[tid];
    const float* wr = W_pool + tid * 128;
    #pragma unroll 8
    for (int d = 0; d < 128; d += 4) {
      float4 wv = *(const float4*)(wr + d);
      float4 pl = *(const float4*)(pooled + pp * 128 + d);
      acc += wv.x * pl.x + wv.y * pl.y + wv.z * pl.z + wv.w * pl.w;
    }
    out[b * 64 + tid] = acc;
  }
}

extern "C" void kernel_launch(void* const* d_in, const int* in_sizes, int n_in,
                              void* d_out, int out_size, void* d_ws, size_t ws_size,
                              hipStream_t stream) {
  const float* x      = (const float*)d_in[0];
  // d_in[1] = batch_indices (unused: equal-length segments)
  const float* W_in   = (const float*)d_in[2];
  const float* b_in   = (const float*)d_in[3];
  const float* W_out  = (const float*)d_in[4];
  const float* b_out  = (const float*)d_in[5];
  const float* W_pool = (const float*)d_in[6];
  const float* b_pool = (const float*)d_in[7];
  unsigned short* wb = (unsigned short*)d_ws;   // 65536 bf16 = 128 KiB

  hipLaunchKernelGGL(wconv_kernel, dim3(256), dim3(256), 0, stream, W_in, W_out, wb);
  hipLaunchKernelGGL(fused_mol_kernel, dim3(8192), dim3(256), 0, stream,
                     x, wb, b_in, b_out, W_pool, b_pool, (float*)d_out);
}